// Round 7
// baseline (2234.952 us; speedup 1.0000x reference)
//
#include <hip/hip_runtime.h>

#define B_   8
#define N_   8192
#define CIN  64
#define COUT 128
#define M_   2048
#define K_   16

typedef float v2f __attribute__((ext_vector_type(2)));
typedef unsigned int v2u __attribute__((ext_vector_type(2)));
typedef unsigned long long ull;

// ---------------------------------------------------------------------------
// DPP wave-64 reduce helpers (VALU-only, no LDS latency).
// ---------------------------------------------------------------------------
template <int CTRL>
__device__ __forceinline__ ull dpp64(ull x) {
  int lo = (int)(unsigned)(x & 0xFFFFFFFFull);
  int hi = (int)(unsigned)(x >> 32);
  int dlo = __builtin_amdgcn_update_dpp(lo, lo, CTRL, 0xF, 0xF, false);
  int dhi = __builtin_amdgcn_update_dpp(hi, hi, CTRL, 0xF, 0xF, false);
  return ((ull)(unsigned)dhi << 32) | (unsigned)dlo;
}

__device__ __forceinline__ ull readlane_u64(ull k, int l) {
  unsigned lo = (unsigned)__builtin_amdgcn_readlane((int)(unsigned)(k & 0xFFFFFFFFull), l);
  unsigned hi = (unsigned)__builtin_amdgcn_readlane((int)(unsigned)(k >> 32), l);
  return ((ull)hi << 32) | lo;
}

__device__ __forceinline__ ull wave_min_u64(ull k) {
  ull t;
  t = dpp64<0x111>(k); k = t < k ? t : k;
  t = dpp64<0x112>(k); k = t < k ? t : k;
  t = dpp64<0x114>(k); k = t < k ? t : k;
  t = dpp64<0x118>(k); k = t < k ? t : k;
  t = dpp64<0x142>(k); k = t < k ? t : k;
  t = dpp64<0x143>(k); k = t < k ? t : k;
  return readlane_u64(k, 63);
}

// 8-bins/axis morton cell id (9 bits). Bin = clamp(floor(v+4), 0, 7).
__device__ __forceinline__ int cell9(float x, float y, float z) {
  int qx = (int)fminf(fmaxf(floorf(x + 4.f), 0.f), 7.f);
  int qy = (int)fminf(fmaxf(floorf(y + 4.f), 0.f), 7.f);
  int qz = (int)fminf(fmaxf(floorf(z + 4.f), 0.f), 7.f);
  int m = 0;
#pragma unroll
  for (int k = 0; k < 3; k++)
    m |= (((qx >> k) & 1) << (3 * k + 2)) | (((qy >> k) & 1) << (3 * k + 1)) |
         (((qz >> k) & 1) << (3 * k));
  return m;
}

// ---------------------------------------------------------------------------
// 1+2) Merged FPS + MLP kernel. Blocks 0..7: FPS; blocks 8..4103: MLP tiles
//      (verbatim). R18 FPS: EXACT block-pruned farthest point sampling.
//
//      * One-time setup: morton counting sort (512 cells) of the 8192 points
//        into spc[] (x,y,z,n_orig); each lane owns 4 subblocks of 8
//        consecutive sorted points (round-robin over waves/lanes so active
//        regions spread evenly); per-subblock bbox + cached max-key.
//      * Per iteration, a subblock is SKIPPED iff clampdist^2(bbox,c) >
//        bd*1.0001. Proof of exactness: fl(dist^2) >= dist^2(1-4e) >=
//        lb^2(1-9e) > bd when fl(lb^2) > bd(1+1e-4)  =>  min(d,dist)=d for
//        every point in the subblock => D2 stays bit-identical to the
//        reference distance array; argmax over it is exact.
//      * Key = (d_bits<<32) | (8191-n_orig)<<13 | n_sorted : max key =
//        (max d, min original n) — identical tie semantics to the verified
//        chain; n_sorted (low 13 bits, unique per point) never flips order
//        and provides the coord lookup for the winner.
//      * Active-path distance update is the VERBATIM R13 pk code (numpy
//        order, no fma, elementwise min).
//      * Decode: lane63 writes wave key; barrier; all lanes read the 4 keys
//        via two broadcast b128 reads + 3 u64 max (no DPP/readlane, no bank
//        conflicts); winner coords from spc[n_sorted]; p_out written in-loop.
// ---------------------------------------------------------------------------
#define FTH 256
#define MROWS2 16 // rows per mlp block (256 threads)

__global__ __launch_bounds__(256, 1) void fps_mlp_kernel(
    const float* __restrict__ p, float* __restrict__ p_out,
    const float* __restrict__ x, const float* __restrict__ W,
    const float* __restrict__ gamma, const float* __restrict__ beta,
    const float* __restrict__ rmean, const float* __restrict__ rvar,
    float* __restrict__ h) {
#pragma clang fp contract(off)
  __shared__ __align__(16) unsigned char smem[139776];

  const int tid = threadIdx.x;

  if (blockIdx.x >= 8) {
    // ---------------- MLP tile (verbatim) ----------------
    float* wt = (float*)smem;                   // W^T padded: wt[c*132+o]
    float* xs = (float*)(smem + 33792);         // xs[r*64+c], 16 rows

    const int o  = tid & 127;
    const int rg = tid >> 7;                    // 0..1 -> rows rg*8..rg*8+7
    const int rowBase = (blockIdx.x - 8) * MROWS2;

    for (int idx = tid; idx < COUT * CIN; idx += 256) {
      const int oo = idx >> 6, cc = idx & 63;
      wt[cc * 132 + oo] = W[idx];
    }
    ((float4*)xs)[tid] = ((const float4*)(x + (size_t)rowBase * CIN))[tid];
    __syncthreads();

    float acc[8] = {0.f, 0.f, 0.f, 0.f, 0.f, 0.f, 0.f, 0.f};
#pragma unroll
    for (int c4 = 0; c4 < CIN / 4; c4++) {
      const float w0 = wt[(4 * c4 + 0) * 132 + o];
      const float w1 = wt[(4 * c4 + 1) * 132 + o];
      const float w2 = wt[(4 * c4 + 2) * 132 + o];
      const float w3 = wt[(4 * c4 + 3) * 132 + o];
#pragma unroll
      for (int i = 0; i < 8; i++) {
        const float4 xv = *(const float4*)&xs[(rg * 8 + i) * CIN + c4 * 4];
        acc[i] += xv.x * w0 + xv.y * w1 + xv.z * w2 + xv.w * w3;
      }
    }
    const float mu = rmean[o];
    const float sc = rsqrtf(rvar[o] + 1e-5f) * gamma[o];
    const float bt = beta[o];
#pragma unroll
    for (int i = 0; i < 8; i++) {
      const float v = (acc[i] - mu) * sc + bt;
      h[(size_t)(rowBase + rg * 8 + i) * COUT + o] = fmaxf(v, 0.f);
    }
    return;
  }

  // ---------------- FPS (R18: exact block pruning) ----------------
  float4* spc = (float4*)smem;                      // 131072 B: sorted pts
  ull (*wred)[4] = (ull (*)[4])(smem + 131072);     // 2*4*8 = 64 B
  int* hA  = (int*)(smem + 131200);                 // 512 ints
  int* hB  = (int*)(smem + 133248);                 // 512 ints
  int* cur = (int*)(smem + 135296);                 // 512 ints

  const int b  = blockIdx.x;
  const int wv = tid >> 6;                          // 0..3
  const int ln = tid & 63;
  const float* pb = p + (size_t)b * N_ * 3;

  // --- counting sort by morton cell ---
  for (int i = tid; i < 512; i += 256) hA[i] = 0;
  __syncthreads();
  for (int n = tid; n < N_; n += 256) {
    float xx = pb[3 * n], yy = pb[3 * n + 1], zz = pb[3 * n + 2];
    atomicAdd(&hA[cell9(xx, yy, zz)], 1);
  }
  __syncthreads();
  {
    int* src = hA; int* dst = hB;
    for (int off = 1; off < 512; off <<= 1) {       // inclusive scan
      for (int i = tid; i < 512; i += 256)
        dst[i] = src[i] + (i >= off ? src[i - off] : 0);
      __syncthreads();
      int* t = src; src = dst; dst = t;
    }
    for (int i = tid; i < 512; i += 256)            // exclusive cursor
      cur[i] = (i ? src[i - 1] : 0);
  }
  __syncthreads();
  for (int n = tid; n < N_; n += 256) {
    float xx = pb[3 * n], yy = pb[3 * n + 1], zz = pb[3 * n + 2];
    int pos = atomicAdd(&cur[cell9(xx, yy, zz)], 1);
    spc[pos] = make_float4(xx, yy, zz, __int_as_float(n));
  }
  __syncthreads();

  // --- first centroid = original point 0 ---
  float cx = pb[0], cy = pb[1], cz = pb[2];
  float* po = p_out + (size_t)b * M_ * 3;
  if (tid == 0) { po[0] = cx; po[1] = cy; po[2] = cz; }

  // --- per-lane: 4 subblocks of 8 sorted points, round-robin spread ---
  const float INF = __builtin_inff();
  v2f X2[16], Y2[16], Z2[16], D2[16];
  v2u LO2[16];
  float blox[4], bhix[4], bloy[4], bhiy[4], bloz[4], bhiz[4];
  ull skey[4]; float bdm[4];
#pragma unroll
  for (int s = 0; s < 4; s++) {
    const int Bq = s * 256 + ln * 4 + wv;           // adjacent blocks ->
    float lx = INF, hx = -INF, ly = INF, hy = -INF, // different waves/lanes
          lz = INF, hz = -INF;
#pragma unroll
    for (int e = 0; e < 8; e++) {
      float4 P = spc[Bq * 8 + e];
      const int jj = s * 4 + (e >> 1);
      const unsigned no = (unsigned)__float_as_int(P.w);
      const unsigned lo =
          (((unsigned)(N_ - 1) - no) << 13) | (unsigned)(Bq * 8 + e);
      if ((e & 1) == 0) { X2[jj].x = P.x; Y2[jj].x = P.y; Z2[jj].x = P.z; LO2[jj].x = lo; }
      else              { X2[jj].y = P.x; Y2[jj].y = P.y; Z2[jj].y = P.z; LO2[jj].y = lo; }
      lx = fminf(lx, P.x); hx = fmaxf(hx, P.x);
      ly = fminf(ly, P.y); hy = fmaxf(hy, P.y);
      lz = fminf(lz, P.z); hz = fmaxf(hz, P.z);
    }
    blox[s] = lx; bhix[s] = hx; bloy[s] = ly; bhiy[s] = hy;
    bloz[s] = lz; bhiz[s] = hz;
    skey[s] = 0ull; bdm[s] = INF;                   // never skip before 1st
  }
#pragma unroll
  for (int j = 0; j < 16; j++) D2[j] = (v2f){INF, INF};

  int buf = 0;
  for (int it = 1; it < M_; ++it) {
    const v2f cxv = {cx, cx}, cyv = {cy, cy}, czv = {cz, cz};
#pragma unroll
    for (int s = 0; s < 4; s++) {
      const float ux = fmaxf(fmaxf(blox[s] - cx, cx - bhix[s]), 0.f);
      const float uy = fmaxf(fmaxf(bloy[s] - cy, cy - bhiy[s]), 0.f);
      const float uz = fmaxf(fmaxf(bloz[s] - cz, cz - bhiz[s]), 0.f);
      const float lb2 = (ux * ux + uy * uy) + uz * uz;
      if (lb2 <= bdm[s]) {                          // ACTIVE (exact-skip test)
        ull rk = 0ull;
#pragma unroll
        for (int q = 0; q < 4; q++) {
          const int jj = s * 4 + q;
          v2f dx = X2[jj] - cxv;
          v2f dy = Y2[jj] - cyv;
          v2f dz = Z2[jj] - czv;
          v2f m1 = dx * dx;
          v2f m2 = dy * dy;
          v2f ss = m1 + m2;
          v2f m3 = dz * dz;
          v2f d  = ss + m3;                         // numpy order, no fma
          v2f dm = __builtin_elementwise_min(D2[jj], d);
          D2[jj] = dm;
          ull ka = ((ull)__float_as_uint(dm.x) << 32) | (ull)LO2[jj].x;
          rk = ka > rk ? ka : rk;
          ull kb = ((ull)__float_as_uint(dm.y) << 32) | (ull)LO2[jj].y;
          rk = kb > rk ? kb : rk;
        }
        skey[s] = rk;
        bdm[s] = __uint_as_float((unsigned)(rk >> 32)) * 1.0001f;
      }
    }
    ull k0 = skey[0] > skey[1] ? skey[0] : skey[1];
    ull k1 = skey[2] > skey[3] ? skey[2] : skey[3];
    ull key = k0 > k1 ? k0 : k1;

    // per-wave max: R13 6-stage u64 DPP ladder; lane 63 writes
    {
      ull t;
      t = dpp64<0x111>(key); key = t > key ? t : key;   // row_shr:1
      t = dpp64<0x112>(key); key = t > key ? t : key;   // row_shr:2
      t = dpp64<0x114>(key); key = t > key ? t : key;   // row_shr:4
      t = dpp64<0x118>(key); key = t > key ? t : key;   // row_shr:8
      t = dpp64<0x142>(key); key = t > key ? t : key;   // row_bcast:15
      t = dpp64<0x143>(key); key = t > key ? t : key;   // row_bcast:31
    }
    if (ln == 63) wred[buf][wv] = key;
    __syncthreads();                            // the ONLY barrier per iter
    // decode: two broadcast b128 reads of the 4 keys + 3 u64 max
    const ulonglong2* wp = (const ulonglong2*)&wred[buf][0];
    ulonglong2 A = wp[0], Bb = wp[1];
    ull w0 = A.x > A.y ? A.x : A.y;
    ull w1 = Bb.x > Bb.y ? Bb.x : Bb.y;
    ull ww = w0 > w1 ? w0 : w1;
    const int ns = (int)(ww & 0x1FFFull);
    float4 cc = spc[ns];                        // 1 broadcast b128
    cx = cc.x; cy = cc.y; cz = cc.z;
    if (tid == 0) { po[3 * it] = cx; po[3 * it + 1] = cy; po[3 * it + 2] = cz; }
    buf ^= 1;
  }
}

// ---------------------------------------------------------------------------
// 3) KNN — VERBATIM from the passing chain. 16 queries/block, p[b]+sn staged
//    in LDS once per block; per-lane sorted top-4 cache, 16 DPP-min rounds,
//    exact rescan; fused gather/max-pool. d2 bits identical.
// ---------------------------------------------------------------------------
#define UMAXK 0xFFFFFFFFFFFFFFFFull
#define QPB  16   // queries (waves) per block

__global__ __launch_bounds__(1024) void knn_kernel(
    const float* __restrict__ p, const float* __restrict__ p_out,
    const float* __restrict__ h, float* __restrict__ y) {
#pragma clang fp contract(off)
  __shared__ float4 pc4[N_];            // 128 KB: x,y,z,sn
  __shared__ int winLds[QPB][K_];

  const int t    = threadIdx.x;
  const int wv   = t >> 6;
  const int lane = t & 63;
  const int b    = blockIdx.x & 7;      // batch: keeps h[b] on one XCD (heur.)
  const int grp  = blockIdx.x >> 3;     // 0..127
  const int q    = b * M_ + grp * QPB + wv;

  const float* pb = p + (size_t)b * N_ * 3;
  for (int n = t; n < N_; n += 1024) {
    float xx = pb[3 * n + 0], yy = pb[3 * n + 1], zz = pb[3 * n + 2];
    float sn = (xx * xx + yy * yy) + zz * zz;   // numpy sum, no fma
    pc4[n] = make_float4(xx, yy, zz, sn);
  }
  __syncthreads();

  const float qx = p_out[q * 3 + 0];
  const float qy = p_out[q * 3 + 1];
  const float qz = p_out[q * 3 + 2];
  const float sq = (qx * qx + qy * qy) + qz * qz;   // numpy sum, no fma

  unsigned long long c0 = UMAXK, c1 = UMAXK, c2 = UMAXK, c3 = UMAXK;
#pragma unroll 4
  for (int j = 0; j < 128; j++) {
    const int n = lane + (j << 6);
    float4 v = pc4[n];
    float dot = __builtin_fmaf(qz, v.z,
                __builtin_fmaf(qy, v.y, qx * v.x)); // BLAS fma chain, k asc
    float d2 = (sq + v.w) - 2.0f * dot;
    unsigned u = __float_as_uint(d2);
    u ^= (unsigned)((int)u >> 31) | 0x80000000u;    // monotone f32->u32
    unsigned long long key = ((unsigned long long)u << 32) | (unsigned)n;
    if (key < c3) {
      unsigned long long x2 = key, mn;
      mn = x2 < c0 ? x2 : c0; x2 = x2 < c0 ? c0 : x2; c0 = mn;
      mn = x2 < c1 ? x2 : c1; x2 = x2 < c1 ? c1 : x2; c1 = mn;
      mn = x2 < c2 ? x2 : c2; x2 = x2 < c2 ? c2 : x2; c2 = mn;
      c3 = x2 < c3 ? x2 : c3;
    }
  }

  int count = 4;
  unsigned long long em0 = 0ull, em1 = 0ull;    // extraction mask (128 bits)
  unsigned long long mykey = UMAXK;             // lane r keeps round-r winner

  for (int k = 0; k < K_; k++) {
    unsigned long long cnd = (count > 0) ? c0 : UMAXK;
    unsigned long long win = wave_min_u64(cnd); // uniform; unique n => exact
    if (lane == k) mykey = win;
    const int nstar = (int)(unsigned)(win & 0xFFFFFFFFu);
    if ((nstar & 63) == lane) {                 // I own the winner (== my c0)
      const int j = nstar >> 6;
      if (j < 64) em0 |= 1ull << j; else em1 |= 1ull << (j - 64);
      c0 = c1; c1 = c2; c2 = c3; c3 = UMAXK; count--;
      if (count == 0 && k < K_ - 1) {           // rare exact rescan from LDS
        c0 = c1 = c2 = c3 = UMAXK;
        for (int j2 = 0; j2 < 128; j2++) {
          bool ex = (j2 < 64) ? ((em0 >> j2) & 1ull) : ((em1 >> (j2 - 64)) & 1ull);
          if (!ex) {
            const int n2 = lane + (j2 << 6);
            float4 v = pc4[n2];
            float dot = __builtin_fmaf(qz, v.z,
                        __builtin_fmaf(qy, v.y, qx * v.x));
            float d2 = (sq + v.w) - 2.0f * dot;
            unsigned u = __float_as_uint(d2);
            u ^= (unsigned)((int)u >> 31) | 0x80000000u;
            unsigned long long kk2 = ((unsigned long long)u << 32) | (unsigned)n2;
            if (kk2 < c3) {
              unsigned long long x2 = kk2, mn;
              mn = x2 < c0 ? x2 : c0; x2 = x2 < c0 ? c0 : x2; c0 = mn;
              mn = x2 < c1 ? x2 : c1; x2 = x2 < c1 ? c1 : x2; c1 = mn;
              mn = x2 < c2 ? x2 : c2; x2 = x2 < c2 ? c2 : x2; c2 = mn;
              c3 = x2 < c3 ? x2 : c3;
            }
          }
        }
        count = 4;
      }
    }
  }

  if (lane < K_) winLds[wv][lane] = (int)(unsigned)(mykey & 0xFFFFFFFFu);
  __syncthreads();

  const float* hb = h + (size_t)b * N_ * COUT;
  float2 acc = make_float2(-__builtin_inff(), -__builtin_inff());
#pragma unroll
  for (int i = 0; i < K_; i++) {
    const int n = winLds[wv][i];                // LDS broadcast read
    float2 v = *(const float2*)(hb + (size_t)n * COUT + lane * 2);
    acc.x = fmaxf(acc.x, v.x);
    acc.y = fmaxf(acc.y, v.y);
  }
  *(float2*)(y + (size_t)q * COUT + lane * 2) = acc;
}

// ---------------------------------------------------------------------------
extern "C" void kernel_launch(void* const* d_in, const int* in_sizes, int n_in,
                              void* d_out, int out_size, void* d_ws, size_t ws_size,
                              hipStream_t stream) {
  const float* x     = (const float*)d_in[0];
  const float* p     = (const float*)d_in[1];
  const float* W     = (const float*)d_in[2];
  const float* gamma = (const float*)d_in[3];
  const float* beta  = (const float*)d_in[4];
  const float* rmean = (const float*)d_in[5];
  const float* rvar  = (const float*)d_in[6];

  float* y     = (float*)d_out;                       // (B, M, COUT)
  float* p_out = y + (size_t)B_ * M_ * COUT;          // (B, M, 3)
  float* h     = (float*)d_ws;                        // (B, N, COUT) scratch

  fps_mlp_kernel<<<8 + (B_ * N_) / MROWS2, 256, 0, stream>>>(
      p, p_out, x, W, gamma, beta, rmean, rvar, h);
  knn_kernel<<<B_ * (M_ / QPB), 1024, 0, stream>>>(p, p_out, h, y);
}